// Round 7
// baseline (1430.029 us; speedup 1.0000x reference)
//
#include <hip/hip_runtime.h>

// LSTMTrafficPredictor: fused 2-layer LSTM + FC head via MFMA (bf16 hi/lo split).
// B=2048, T=512, IN=4, H1=64, H2=32, FC=16, OUT=1.
// R7 structure (from R6 post-mortem: 3 barriers/step + gate-LDS round trips +
// 5e7 bank-conflict cycles were the bottleneck):
//  1. Gate-complete tile mapping: weight fragments are built so each lane's
//     accumulators hold ALL FOUR gates (i,f,g,o) of its own units ->
//     activations fully in-register, c1/c2 lane-resident, NO gate LDS.
//  2. Layer-2 pipelined one step behind: iter s computes gates1(s) AND
//     gates2(s-1) in ONE MFMA burst (54 MFMA/wave, 6 independent acc chains).
//  3. Ping-pong z buffers: read [p], write [1-p] -> ONE barrier per step.
//  4. Fragment-major z layout: frag read = ds_read_b128 at lane*16 (canonical
//     contiguous, conflict-minimal); h-writes are aligned b64.
// Precision: v = hi + lo (bf16); gate = Whi@zhi + Whi@zlo + Wlo@zhi (as R5/R6,
// absmax 6e-5). Block = 4 batches (MFMA cols 4..15 padded), 256 thr, grid 512
// -> 2 blocks/CU.
// z element offset for (k, batch n): off = (k>>5)*512 + (((k>>3)&3)*16+n)*8 + (k&7)
//   layer1 z (zA): k = [x(4) | h1(64) | bias-one(1) | 0-pad] K=96
//   layer2 z (zB): k = [h1(64) | h2(32)] K=96

#define T_LEN 512
#define IN_F  4
#define H1    64
#define H2    32
#define FCN   16
#define MB    4
#define BLK   256

typedef __attribute__((ext_vector_type(8))) short          s8b;  // 8 bf16
typedef __attribute__((ext_vector_type(4))) float          f4;   // MFMA acc
typedef __attribute__((ext_vector_type(4))) unsigned short u4s;  // 4 bf16 store

union S8U { s8b v; unsigned short u[8]; };

__device__ __forceinline__ float sigm(float x)  { return 1.0f / (1.0f + __expf(-x)); }
__device__ __forceinline__ float tanh_(float x) { return 1.0f - 2.0f / (__expf(2.0f * x) + 1.0f); }

__device__ __forceinline__ unsigned short bf16_rne(float f) {
    unsigned u = __float_as_uint(f);
    u = u + 0x7FFFu + ((u >> 16) & 1u);
    return (unsigned short)(u >> 16);
}
__device__ __forceinline__ float bf16_f(unsigned short h) {
    return __uint_as_float(((unsigned)h) << 16);
}

__global__ __launch_bounds__(BLK, 2)
void lstm_mfma(const float* __restrict__ x,
               const float* __restrict__ Wih1, const float* __restrict__ Whh1,
               const float* __restrict__ bih1, const float* __restrict__ bhh1,
               const float* __restrict__ Wih2, const float* __restrict__ Whh2,
               const float* __restrict__ bih2, const float* __restrict__ bhh2,
               const float* __restrict__ fc1_w, const float* __restrict__ fc1_b,
               const float* __restrict__ fc2_w, const float* __restrict__ fc2_b,
               float* __restrict__ out)
{
    // [pingpong][hi/lo][3 ks-blocks * 512 elems]
    __shared__ __align__(16) unsigned short zA[2][2][1536];   // 12 KB
    __shared__ __align__(16) unsigned short zB[2][2][1536];   // 12 KB
    __shared__ __align__(16) float h2f[MB * H2];
    __shared__ __align__(16) float fcs[MB * FCN];

    const int t    = threadIdx.x;
    const int lane = t & 63;
    const int w    = t >> 6;      // wave 0..3
    const int col  = lane & 15;   // batch (valid < MB) / A-frag row
    const int quad = lane >> 4;
    const int b0   = blockIdx.x * MB;

    // ---- weight fragments (gate-complete mapping) ----
    // layer1 tile nt (nt = gate type): A row m -> global gate row nt*64 + w*16 + m
    //   => lane acc1[nt][rg] = gate nt, unit w*16+quad*4+rg, batch col
    // layer2 tile nt (nt in 0..1): A row m -> row (m&3)*32 + w*8 + (m>>2) + nt*4
    //   => lane acc2[nt][rg] = gate rg, unit w*8+quad+nt*4, batch col
    S8U wf1h[4][3], wf1l[4][3], wf2h[2][3], wf2l[2][3];
    #pragma unroll
    for (int nt = 0; nt < 4; ++nt) {
        const int r1 = nt * 64 + w * 16 + col;
        #pragma unroll
        for (int ks = 0; ks < 3; ++ks) {
            #pragma unroll
            for (int j = 0; j < 8; ++j) {
                const int k = ks * 32 + quad * 8 + j;
                float wv;
                if      (k < IN_F)       wv = Wih1[r1 * IN_F + k];
                else if (k < IN_F + H1)  wv = Whh1[r1 * H1 + (k - IN_F)];
                else if (k == IN_F + H1) wv = bih1[r1] + bhh1[r1];   // bias col
                else                     wv = 0.f;
                const unsigned short hh = bf16_rne(wv);
                wf1h[nt][ks].u[j] = hh;
                wf1l[nt][ks].u[j] = bf16_rne(wv - bf16_f(hh));
            }
        }
    }
    #pragma unroll
    for (int nt = 0; nt < 2; ++nt) {
        const int r2 = (col & 3) * 32 + w * 8 + (col >> 2) + nt * 4;
        #pragma unroll
        for (int ks = 0; ks < 3; ++ks) {
            #pragma unroll
            for (int j = 0; j < 8; ++j) {
                const int k = ks * 32 + quad * 8 + j;
                const float wv = (k < H1) ? Wih2[r2 * H1 + k]
                                          : Whh2[r2 * H2 + (k - H1)];
                const unsigned short hh = bf16_rne(wv);
                wf2h[nt][ks].u[j] = hh;
                wf2l[nt][ks].u[j] = bf16_rne(wv - bf16_f(hh));
            }
        }
    }

    // ---- layer2 biases for this lane's units ----
    float bI[2], bF[2], bG[2], bO[2];
    #pragma unroll
    for (int nt = 0; nt < 2; ++nt) {
        const int u2 = w * 8 + quad + nt * 4;
        bI[nt] = bih2[u2]      + bhh2[u2];
        bF[nt] = bih2[32 + u2] + bhh2[32 + u2];
        bG[nt] = bih2[64 + u2] + bhh2[64 + u2];
        bO[nt] = bih2[96 + u2] + bhh2[96 + u2];
    }

    // ---- init LDS: zero z, bias-one column (both pingpong), x(0) ----
    {
        int* pa = (int*)zA; int* pb = (int*)zB;
        for (int i = t; i < 3072; i += BLK) { pa[i] = 0; pb[i] = 0; }
    }
    __syncthreads();
    if (t < MB) {
        zA[0][0][1024 + t * 8 + 4] = 0x3F80;   // off(k=68, n=t): bias-one, hi
        zA[1][0][1024 + t * 8 + 4] = 0x3F80;
    }
    if (t < MB * IN_F) {
        const int n = t >> 2, f = t & 3;
        const float xv = x[(size_t)(b0 + n) * T_LEN * IN_F + f];
        const unsigned short xh = bf16_rne(xv);
        zA[0][0][n * 8 + f] = xh;              // off(k=f, n) = n*8+f
        zA[0][1][n * 8 + f] = bf16_rne(xv - bf16_f(xh));
    }
    float c1[4] = {0.f, 0.f, 0.f, 0.f};   // units w*16+quad*4+rg, batch col
    float c2[2] = {0.f, 0.f};             // units w*8+quad+nt*4,  batch col

    // precomputed write offsets (element index), used when col < MB
    const int kA   = IN_F + w * 16 + quad * 4;
    const int offA = (kA >> 5) * 512 + (((kA >> 3) & 3) * 16 + col) * 8 + (kA & 7);
    const int kB   = w * 16 + quad * 4;
    const int offB = (kB >> 5) * 512 + (((kB >> 3) & 3) * 16 + col) * 8 + (kB & 7);
    const int offF = lane * 8;            // frag read base (elements)
    __syncthreads();

    // ================= main recurrence: ONE barrier per step =================
    #pragma unroll 1
    for (int s = 0; s < T_LEN; ++s) {
        const int p = s & 1, np = p ^ 1;

        // x(s+1) prefetch (consumed at step end)
        float xnext = 0.f;
        if (t < MB * IN_F && s < T_LEN - 1)
            xnext = x[(size_t)(b0 + (t >> 2)) * T_LEN * IN_F + (s + 1) * IN_F + (t & 3)];

        // ---- fragment reads: canonical contiguous (lane*16B) ----
        s8b zah[3], zal[3], zbh[3], zbl[3];
        #pragma unroll
        for (int ks = 0; ks < 3; ++ks) {
            zah[ks] = *(const s8b*)(&zA[p][0][0] + ks * 512 + offF);
            zal[ks] = *(const s8b*)(&zA[p][1][0] + ks * 512 + offF);
            zbh[ks] = *(const s8b*)(&zB[p][0][0] + ks * 512 + offF);
            zbl[ks] = *(const s8b*)(&zB[p][1][0] + ks * 512 + offF);
        }

        // ---- one MFMA burst: gates1(s) + gates2(s-1), 6 independent chains ----
        f4 acc1[4] = {{0,0,0,0},{0,0,0,0},{0,0,0,0},{0,0,0,0}};
        f4 acc2[2] = {{0,0,0,0},{0,0,0,0}};
        #pragma unroll
        for (int ks = 0; ks < 3; ++ks) {
            #pragma unroll
            for (int nt = 0; nt < 4; ++nt) {
                acc1[nt] = __builtin_amdgcn_mfma_f32_16x16x32_bf16(wf1h[nt][ks].v, zah[ks], acc1[nt], 0, 0, 0);
                acc1[nt] = __builtin_amdgcn_mfma_f32_16x16x32_bf16(wf1h[nt][ks].v, zal[ks], acc1[nt], 0, 0, 0);
                acc1[nt] = __builtin_amdgcn_mfma_f32_16x16x32_bf16(wf1l[nt][ks].v, zah[ks], acc1[nt], 0, 0, 0);
            }
            #pragma unroll
            for (int nt = 0; nt < 2; ++nt) {
                acc2[nt] = __builtin_amdgcn_mfma_f32_16x16x32_bf16(wf2h[nt][ks].v, zbh[ks], acc2[nt], 0, 0, 0);
                acc2[nt] = __builtin_amdgcn_mfma_f32_16x16x32_bf16(wf2h[nt][ks].v, zbl[ks], acc2[nt], 0, 0, 0);
                acc2[nt] = __builtin_amdgcn_mfma_f32_16x16x32_bf16(wf2l[nt][ks].v, zbh[ks], acc2[nt], 0, 0, 0);
            }
        }

        // ---- layer1 activations in-register (bias via bias column) ----
        u4s hh4, hl4;
        #pragma unroll
        for (int rg = 0; rg < 4; ++rg) {
            const float I = sigm(acc1[0][rg]);
            const float F = sigm(acc1[1][rg]);
            const float G = tanh_(acc1[2][rg]);
            const float O = sigm(acc1[3][rg]);
            c1[rg] = fmaf(F, c1[rg], I * G);
            const float h = O * tanh_(c1[rg]);
            const unsigned short hh = bf16_rne(h);
            hh4[rg] = hh;
            hl4[rg] = bf16_rne(h - bf16_f(hh));
        }
        if (col < MB) {
            *(u4s*)(&zA[np][0][0] + offA) = hh4;
            *(u4s*)(&zA[np][1][0] + offA) = hl4;
            *(u4s*)(&zB[np][0][0] + offB) = hh4;
            *(u4s*)(&zB[np][1][0] + offB) = hl4;
        }

        // ---- layer2 activations for step s-1 (skip at s=0) ----
        if (s > 0) {
            #pragma unroll
            for (int nt = 0; nt < 2; ++nt) {
                const float I = sigm(acc2[nt][0] + bI[nt]);
                const float F = sigm(acc2[nt][1] + bF[nt]);
                const float G = tanh_(acc2[nt][2] + bG[nt]);
                const float O = sigm(acc2[nt][3] + bO[nt]);
                c2[nt] = fmaf(F, c2[nt], I * G);
                const float h = O * tanh_(c2[nt]);
                if (col < MB) {
                    // off(k=64+u2, n=col) = 1024 + (w*16+col)*8 + quad + 4*nt
                    const int o2 = 1024 + (w * 16 + col) * 8 + quad + 4 * nt;
                    const unsigned short hh = bf16_rne(h);
                    zB[np][0][o2] = hh;
                    zB[np][1][o2] = bf16_rne(h - bf16_f(hh));
                }
            }
        }

        // ---- x(s+1) into zA[np] ----
        if (t < MB * IN_F && s < T_LEN - 1) {
            const unsigned short xh = bf16_rne(xnext);
            zA[np][0][(t >> 2) * 8 + (t & 3)] = xh;
            zA[np][1][(t >> 2) * 8 + (t & 3)] = bf16_rne(xnext - bf16_f(xh));
        }
        __syncthreads();
    }

    // ================= epilogue: layer2 step T-1 =================
    {
        // after loop: p = 512&1 = 0; zB[0] holds [h1(T-1), h2(T-2)]
        s8b zbh[3], zbl[3];
        #pragma unroll
        for (int ks = 0; ks < 3; ++ks) {
            zbh[ks] = *(const s8b*)(&zB[0][0][0] + ks * 512 + offF);
            zbl[ks] = *(const s8b*)(&zB[0][1][0] + ks * 512 + offF);
        }
        f4 acc2[2] = {{0,0,0,0},{0,0,0,0}};
        #pragma unroll
        for (int ks = 0; ks < 3; ++ks) {
            #pragma unroll
            for (int nt = 0; nt < 2; ++nt) {
                acc2[nt] = __builtin_amdgcn_mfma_f32_16x16x32_bf16(wf2h[nt][ks].v, zbh[ks], acc2[nt], 0, 0, 0);
                acc2[nt] = __builtin_amdgcn_mfma_f32_16x16x32_bf16(wf2h[nt][ks].v, zbl[ks], acc2[nt], 0, 0, 0);
                acc2[nt] = __builtin_amdgcn_mfma_f32_16x16x32_bf16(wf2l[nt][ks].v, zbh[ks], acc2[nt], 0, 0, 0);
            }
        }
        #pragma unroll
        for (int nt = 0; nt < 2; ++nt) {
            const float I = sigm(acc2[nt][0] + bI[nt]);
            const float F = sigm(acc2[nt][1] + bF[nt]);
            const float G = tanh_(acc2[nt][2] + bG[nt]);
            const float O = sigm(acc2[nt][3] + bO[nt]);
            c2[nt] = fmaf(F, c2[nt], I * G);
            const float h = O * tanh_(c2[nt]);
            if (col < MB) h2f[col * H2 + (w * 8 + quad + nt * 4)] = h;
        }
    }
    __syncthreads();

    // ================= FC head =================
    if (t < MB * FCN) {
        const int b = t >> 4, j = t & 15;
        float s1 = fc1_b[j];
        #pragma unroll
        for (int k = 0; k < H2; ++k)
            s1 = fmaf(fc1_w[j * H2 + k], h2f[b * H2 + k], s1);
        fcs[b * FCN + j] = fmaxf(s1, 0.f);
    }
    __syncthreads();
    if (t < MB) {
        float s2 = fc2_b[0];
        #pragma unroll
        for (int j = 0; j < FCN; ++j)
            s2 = fmaf(fc2_w[j], fcs[t * FCN + j], s2);
        out[b0 + t] = s2;
    }
}

extern "C" void kernel_launch(void* const* d_in, const int* in_sizes, int n_in,
                              void* d_out, int out_size, void* d_ws, size_t ws_size,
                              hipStream_t stream) {
    const float* x     = (const float*)d_in[0];
    const float* Wih1  = (const float*)d_in[1];
    const float* Whh1  = (const float*)d_in[2];
    const float* bih1  = (const float*)d_in[3];
    const float* bhh1  = (const float*)d_in[4];
    const float* Wih2  = (const float*)d_in[5];
    const float* Whh2  = (const float*)d_in[6];
    const float* bih2  = (const float*)d_in[7];
    const float* bhh2  = (const float*)d_in[8];
    const float* fc1_w = (const float*)d_in[9];
    const float* fc1_b = (const float*)d_in[10];
    const float* fc2_w = (const float*)d_in[11];
    const float* fc2_b = (const float*)d_in[12];
    float* out = (float*)d_out;

    const int n_batch = 2048;
    dim3 grid(n_batch / MB), block(BLK);
    lstm_mfma<<<grid, block, 0, stream>>>(x, Wih1, Whh1, bih1, bhh1,
                                          Wih2, Whh2, bih2, bhh2,
                                          fc1_w, fc1_b, fc2_w, fc2_b, out);
}

// Round 8
// 867.220 us; speedup vs baseline: 1.6490x; 1.6490x over previous
//
#include <hip/hip_runtime.h>

// LSTMTrafficPredictor: fused 2-layer LSTM + FC head via MFMA (bf16 hi/lo split).
// B=2048, T=512, IN=4, H1=64, H2=32, FC=16, OUT=1.
// R8: R7's structure (1 barrier/step, ping-pong z, gate-complete tiles,
// conflict-free frag layout: verified 2.5e4 conflict cycles) but sized so
// registers actually FIT: R7 needed 144 VGPR of weights + 24 acc + 48 frags
// ~= the whole 256 budget -> allocator refetched weights every step
// (VALUBusy 76%). R8: BLK=512 (8 waves), MB=8, grid=256 -> per-wave weights
// 80 VGPR (L1: 2 tiles, L2: 1 tile), total ~170 < 256 (launch_bounds(512,2)).
// Single merged z buffer (h1 shared by both layers, written once):
//   k-map (K=128, 4 ks-blocks): [x(0..3) | h1(4..67) | bias-one(68) |
//                                0-pad(69..95) | h2(96..127)]
//   layer1 weights cover ks 0..2 (bias via col 68); layer2 weights cover
//   ks 0..3 with zeros outside h1/h2 cols, layer2 bias ALSO via col 68.
// Gate-complete interleaved tiles: tile row m -> gate m&3, unit m>>2
//   L1 tile nt (nt=0,1), wave w: unit = w*8 + nt*4 + quad; acc[rg] = gate rg
//   L2 tile, wave w:             unit = w*4 + quad;        acc[rg] = gate rg
// z element offset for (k, batch n):
//   off = (k>>5)*512 + (((k>>3)&3)*16 + n)*8 + (k&7)  -> frag read = lane*8.
// Precision: v = hi+lo (bf16); gate = Whi@zhi + Whi@zlo + Wlo@zhi (absmax 6e-5).

#define T_LEN 512
#define IN_F  4
#define H1    64
#define H2    32
#define FCN   16
#define MB    8
#define BLK   512

typedef __attribute__((ext_vector_type(8))) short s8b;  // 8 bf16 = 4 VGPR
typedef __attribute__((ext_vector_type(4))) float f4;   // MFMA acc

union S8U { s8b v; unsigned short u[8]; };

__device__ __forceinline__ float sigm(float x)  { return 1.0f / (1.0f + __expf(-x)); }
__device__ __forceinline__ float tanh_(float x) { return 1.0f - 2.0f / (__expf(2.0f * x) + 1.0f); }

__device__ __forceinline__ unsigned short bf16_rne(float f) {
    unsigned u = __float_as_uint(f);
    u = u + 0x7FFFu + ((u >> 16) & 1u);
    return (unsigned short)(u >> 16);
}
__device__ __forceinline__ float bf16_f(unsigned short h) {
    return __uint_as_float(((unsigned)h) << 16);
}

__global__ __launch_bounds__(BLK, 2)
void lstm_mfma(const float* __restrict__ x,
               const float* __restrict__ Wih1, const float* __restrict__ Whh1,
               const float* __restrict__ bih1, const float* __restrict__ bhh1,
               const float* __restrict__ Wih2, const float* __restrict__ Whh2,
               const float* __restrict__ bih2, const float* __restrict__ bhh2,
               const float* __restrict__ fc1_w, const float* __restrict__ fc1_b,
               const float* __restrict__ fc2_w, const float* __restrict__ fc2_b,
               float* __restrict__ out)
{
    __shared__ __align__(16) unsigned short zz[2][2][2048];  // [pp][hi/lo][4ks*512] 16 KB
    __shared__ __align__(16) float h2f[MB * H2];
    __shared__ __align__(16) float fcs[MB * FCN];

    const int t    = threadIdx.x;
    const int lane = t & 63;
    const int w    = t >> 6;      // wave 0..7
    const int col  = lane & 15;   // batch col (valid < MB) / A-frag row
    const int quad = lane >> 4;
    const int b0   = blockIdx.x * MB;

    // ---- weight fragments (gate-complete interleaved mapping) ----
    S8U wf1h[2][3], wf1l[2][3];   // layer1: 2 tiles x ks 0..2
    S8U wf2h[4],    wf2l[4];      // layer2: 1 tile  x ks 0..3
    #pragma unroll
    for (int nt = 0; nt < 2; ++nt) {
        const int r1 = (col & 3) * 64 + w * 8 + nt * 4 + (col >> 2);
        #pragma unroll
        for (int ks = 0; ks < 3; ++ks) {
            #pragma unroll
            for (int j = 0; j < 8; ++j) {
                const int k = ks * 32 + quad * 8 + j;
                float wv;
                if      (k < IN_F)       wv = Wih1[r1 * IN_F + k];
                else if (k < IN_F + H1)  wv = Whh1[r1 * H1 + (k - IN_F)];
                else if (k == IN_F + H1) wv = bih1[r1] + bhh1[r1];   // bias col
                else                     wv = 0.f;
                const unsigned short hh = bf16_rne(wv);
                wf1h[nt][ks].u[j] = hh;
                wf1l[nt][ks].u[j] = bf16_rne(wv - bf16_f(hh));
            }
        }
    }
    {
        const int r2 = (col & 3) * 32 + w * 4 + (col >> 2);
        #pragma unroll
        for (int ks = 0; ks < 4; ++ks) {
            #pragma unroll
            for (int j = 0; j < 8; ++j) {
                const int k = ks * 32 + quad * 8 + j;
                float wv;
                if      (k >= IN_F && k < IN_F + H1) wv = Wih2[r2 * H1 + (k - IN_F)];
                else if (k == IN_F + H1)             wv = bih2[r2] + bhh2[r2]; // bias col
                else if (k >= 96)                    wv = Whh2[r2 * H2 + (k - 96)];
                else                                 wv = 0.f;
                const unsigned short hh = bf16_rne(wv);
                wf2h[ks].u[j] = hh;
                wf2l[ks].u[j] = bf16_rne(wv - bf16_f(hh));
            }
        }
    }

    // ---- init LDS: zero z; bias-one col (both pp); x(0) ----
    {
        int* pz = (int*)zz;
        #pragma unroll
        for (int i = 0; i < 8; ++i) pz[t + i * BLK] = 0;
    }
    __syncthreads();
    if (t < 16) {                           // off(k=68,n) = 1024 + n*8 + 4
        zz[0][0][1024 + t * 8 + 4] = 0x3F80;
        zz[1][0][1024 + t * 8 + 4] = 0x3F80;
    }
    if (t < MB * IN_F) {
        const int n = t >> 2, f = t & 3;
        const float xv = x[(size_t)(b0 + n) * T_LEN * IN_F + f];
        const unsigned short xh = bf16_rne(xv);
        zz[0][0][n * 8 + f] = xh;           // off(k=f,n) = n*8 + f
        zz[0][1][n * 8 + f] = bf16_rne(xv - bf16_f(xh));
    }
    float c1[2] = {0.f, 0.f};   // layer1 units w*8+nt*4+quad, batch col
    float c2    = 0.f;          // layer2 unit  w*4+quad,      batch col

    // precomputed store offsets (element index)
    const int u1a  = w * 8 + quad;                 // nt=0 unit
    const int u1b  = w * 8 + 4 + quad;             // nt=1 unit
    const int kA0  = IN_F + u1a, kA1 = IN_F + u1b;
    const int off1a = (kA0 >> 5) * 512 + (((kA0 >> 3) & 3) * 16 + col) * 8 + (kA0 & 7);
    const int off1b = (kA1 >> 5) * 512 + (((kA1 >> 3) & 3) * 16 + col) * 8 + (kA1 & 7);
    const int u2    = w * 4 + quad;
    const int off2  = 1536 + (((u2 >> 3) & 3) * 16 + col) * 8 + (u2 & 7);
    const int offF  = lane * 8;                    // frag read base
    __syncthreads();

    // ================= main recurrence: ONE barrier per step =================
    #pragma unroll 1
    for (int s = 0; s < T_LEN; ++s) {
        const int p = s & 1, np = p ^ 1;

        float xnext = 0.f;
        if (t < MB * IN_F && s < T_LEN - 1)
            xnext = x[(size_t)(b0 + (t >> 2)) * T_LEN * IN_F + (s + 1) * IN_F + (t & 3)];

        // ---- fragment reads (contiguous lane*16B; conflict-free per R7) ----
        s8b zh[4], zl[4];
        #pragma unroll
        for (int ks = 0; ks < 4; ++ks) {
            zh[ks] = *(const s8b*)(&zz[p][0][0] + ks * 512 + offF);
            zl[ks] = *(const s8b*)(&zz[p][1][0] + ks * 512 + offF);
        }

        // ---- MFMA burst: gates1(s) (2 tiles) + gates2(s-1) (1 tile) ----
        f4 acc1[2] = {{0,0,0,0},{0,0,0,0}};
        f4 acc2 = {0,0,0,0};
        #pragma unroll
        for (int ks = 0; ks < 3; ++ks) {
            #pragma unroll
            for (int nt = 0; nt < 2; ++nt) {
                acc1[nt] = __builtin_amdgcn_mfma_f32_16x16x32_bf16(wf1h[nt][ks].v, zh[ks], acc1[nt], 0, 0, 0);
                acc1[nt] = __builtin_amdgcn_mfma_f32_16x16x32_bf16(wf1h[nt][ks].v, zl[ks], acc1[nt], 0, 0, 0);
                acc1[nt] = __builtin_amdgcn_mfma_f32_16x16x32_bf16(wf1l[nt][ks].v, zh[ks], acc1[nt], 0, 0, 0);
            }
        }
        #pragma unroll
        for (int ks = 0; ks < 4; ++ks) {
            acc2 = __builtin_amdgcn_mfma_f32_16x16x32_bf16(wf2h[ks].v, zh[ks], acc2, 0, 0, 0);
            acc2 = __builtin_amdgcn_mfma_f32_16x16x32_bf16(wf2h[ks].v, zl[ks], acc2, 0, 0, 0);
            acc2 = __builtin_amdgcn_mfma_f32_16x16x32_bf16(wf2l[ks].v, zh[ks], acc2, 0, 0, 0);
        }

        // ---- layer1 activations in-register (acc[rg] = gate rg: i,f,g,o) ----
        #pragma unroll
        for (int nt = 0; nt < 2; ++nt) {
            const float I = sigm(acc1[nt][0]);
            const float F = sigm(acc1[nt][1]);
            const float G = tanh_(acc1[nt][2]);
            const float O = sigm(acc1[nt][3]);
            c1[nt] = fmaf(F, c1[nt], I * G);
            const float h = O * tanh_(c1[nt]);
            const unsigned short hh = bf16_rne(h);
            const unsigned short hl = bf16_rne(h - bf16_f(hh));
            if (col < MB) {
                const int o = nt ? off1b : off1a;
                zz[np][0][o] = hh;
                zz[np][1][o] = hl;
            }
        }

        // ---- layer2 activation for step s-1 (bias came via bias column) ----
        if (s > 0) {
            const float I = sigm(acc2[0]);
            const float F = sigm(acc2[1]);
            const float G = tanh_(acc2[2]);
            const float O = sigm(acc2[3]);
            c2 = fmaf(F, c2, I * G);
            const float h = O * tanh_(c2);
            if (col < MB) {
                const unsigned short hh = bf16_rne(h);
                zz[np][0][off2] = hh;
                zz[np][1][off2] = bf16_rne(h - bf16_f(hh));
            }
        }

        // ---- x(s+1) ----
        if (t < MB * IN_F && s < T_LEN - 1) {
            const unsigned short xh = bf16_rne(xnext);
            zz[np][0][(t >> 2) * 8 + (t & 3)] = xh;
            zz[np][1][(t >> 2) * 8 + (t & 3)] = bf16_rne(xnext - bf16_f(xh));
        }
        __syncthreads();
    }

    // ================= epilogue: layer2 step T-1 =================
    {
        // loop ended with s=511 (p=1, np=0): z[0] holds h1(511), h2(510).
        s8b zh[4], zl[4];
        #pragma unroll
        for (int ks = 0; ks < 4; ++ks) {
            zh[ks] = *(const s8b*)(&zz[0][0][0] + ks * 512 + offF);
            zl[ks] = *(const s8b*)(&zz[0][1][0] + ks * 512 + offF);
        }
        f4 acc2 = {0,0,0,0};
        #pragma unroll
        for (int ks = 0; ks < 4; ++ks) {
            acc2 = __builtin_amdgcn_mfma_f32_16x16x32_bf16(wf2h[ks].v, zh[ks], acc2, 0, 0, 0);
            acc2 = __builtin_amdgcn_mfma_f32_16x16x32_bf16(wf2h[ks].v, zl[ks], acc2, 0, 0, 0);
            acc2 = __builtin_amdgcn_mfma_f32_16x16x32_bf16(wf2l[ks].v, zh[ks], acc2, 0, 0, 0);
        }
        const float I = sigm(acc2[0]);
        const float F = sigm(acc2[1]);
        const float G = tanh_(acc2[2]);
        const float O = sigm(acc2[3]);
        c2 = fmaf(F, c2, I * G);
        if (col < MB) h2f[col * H2 + u2] = O * tanh_(c2);
    }
    __syncthreads();

    // ================= FC head =================
    if (t < MB * FCN) {
        const int b = t >> 4, j = t & 15;
        float s1 = fc1_b[j];
        #pragma unroll
        for (int k = 0; k < H2; ++k)
            s1 = fmaf(fc1_w[j * H2 + k], h2f[b * H2 + k], s1);
        fcs[b * FCN + j] = fmaxf(s1, 0.f);
    }
    __syncthreads();
    if (t < MB) {
        float s2 = fc2_b[0];
        #pragma unroll
        for (int j = 0; j < FCN; ++j)
            s2 = fmaf(fc2_w[j], fcs[t * FCN + j], s2);
        out[b0 + t] = s2;
    }
}

extern "C" void kernel_launch(void* const* d_in, const int* in_sizes, int n_in,
                              void* d_out, int out_size, void* d_ws, size_t ws_size,
                              hipStream_t stream) {
    const float* x     = (const float*)d_in[0];
    const float* Wih1  = (const float*)d_in[1];
    const float* Whh1  = (const float*)d_in[2];
    const float* bih1  = (const float*)d_in[3];
    const float* bhh1  = (const float*)d_in[4];
    const float* Wih2  = (const float*)d_in[5];
    const float* Whh2  = (const float*)d_in[6];
    const float* bih2  = (const float*)d_in[7];
    const float* bhh2  = (const float*)d_in[8];
    const float* fc1_w = (const float*)d_in[9];
    const float* fc1_b = (const float*)d_in[10];
    const float* fc2_w = (const float*)d_in[11];
    const float* fc2_b = (const float*)d_in[12];
    float* out = (float*)d_out;

    const int n_batch = 2048;
    dim3 grid(n_batch / MB), block(BLK);
    lstm_mfma<<<grid, block, 0, stream>>>(x, Wih1, Whh1, bih1, bhh1,
                                          Wih2, Whh2, bih2, bhh2,
                                          fc1_w, fc1_b, fc2_w, fc2_b, out);
}

// Round 9
// 852.575 us; speedup vs baseline: 1.6773x; 1.0172x over previous
//
#include <hip/hip_runtime.h>

// LSTMTrafficPredictor: fused 2-layer LSTM + FC head via MFMA (bf16 hi/lo split).
// B=2048, T=512, IN=4, H1=64, H2=32, FC=16, OUT=1.
// R9 = R8 + AGPR-pinned weight fragments.
// R8 post-mortem: VGPR_Count=76 (< the 80 VGPR of weight fragments) and
// VALUBusy=65% => ~650 VALU instr/wave/step vs ~130 legitimate. The compiler
// REMATERIALIZES the whole fragment construction (global loads + bf16_rne)
// inside the step loop. Fix: pin each fragment into AGPRs with "+a" inline
// asm after construction — an asm def cannot be rematerialized, and gfx950
// MFMA reads AGPR operands natively (no per-use copy, unlike R4's VALU case).
// Structure unchanged from R8 (verified: 1 barrier/step, ping-pong merged z,
// gate-complete tiles, conflict-free frag layout, absmax 6.1e-5):
//   BLK=512 (8 waves), MB=8, grid=256.
//   k-map (K=128): [x(0..3) | h1(4..67) | bias-one(68) | 0(69..95) | h2(96..127)]
//   L1: 2 tiles/wave (unit w*8+nt*4+quad, acc[rg]=gate rg), ks 0..2
//   L2: 1 tile/wave  (unit w*4+quad,      acc[rg]=gate rg), ks 0..3
//   z offset(k,n) = (k>>5)*512 + (((k>>3)&3)*16+n)*8 + (k&7); frag read = lane*8.

#define T_LEN 512
#define IN_F  4
#define H1    64
#define H2    32
#define FCN   16
#define MB    8
#define BLK   512

typedef __attribute__((ext_vector_type(8))) short s8b;  // 8 bf16 = 4 VGPR
typedef __attribute__((ext_vector_type(4))) float f4;   // MFMA acc
typedef __attribute__((ext_vector_type(4))) int   i4;   // 4 dwords (pin unit)

union S8U { s8b v; i4 d; unsigned short u[8]; };

// Pin 4 consecutive regs into AGPRs; asm def kills rematerialization.
#define APIN4(x) asm volatile("" : "+a"((x).d))

__device__ __forceinline__ float sigm(float x)  { return 1.0f / (1.0f + __expf(-x)); }
__device__ __forceinline__ float tanh_(float x) { return 1.0f - 2.0f / (__expf(2.0f * x) + 1.0f); }

__device__ __forceinline__ unsigned short bf16_rne(float f) {
    unsigned u = __float_as_uint(f);
    u = u + 0x7FFFu + ((u >> 16) & 1u);
    return (unsigned short)(u >> 16);
}
__device__ __forceinline__ float bf16_f(unsigned short h) {
    return __uint_as_float(((unsigned)h) << 16);
}

__global__ __launch_bounds__(BLK, 2)
void lstm_mfma(const float* __restrict__ x,
               const float* __restrict__ Wih1, const float* __restrict__ Whh1,
               const float* __restrict__ bih1, const float* __restrict__ bhh1,
               const float* __restrict__ Wih2, const float* __restrict__ Whh2,
               const float* __restrict__ bih2, const float* __restrict__ bhh2,
               const float* __restrict__ fc1_w, const float* __restrict__ fc1_b,
               const float* __restrict__ fc2_w, const float* __restrict__ fc2_b,
               float* __restrict__ out)
{
    __shared__ __align__(16) unsigned short zz[2][2][2048];  // [pp][hi/lo][4ks*512] 16 KB
    __shared__ __align__(16) float h2f[MB * H2];
    __shared__ __align__(16) float fcs[MB * FCN];

    const int t    = threadIdx.x;
    const int lane = t & 63;
    const int w    = t >> 6;      // wave 0..7
    const int col  = lane & 15;   // batch col (valid < MB) / A-frag row
    const int quad = lane >> 4;
    const int b0   = blockIdx.x * MB;

    // ---- weight fragments (gate-complete interleaved mapping) ----
    S8U wf1h[2][3], wf1l[2][3];   // layer1: 2 tiles x ks 0..2
    S8U wf2h[4],    wf2l[4];      // layer2: 1 tile  x ks 0..3
    #pragma unroll
    for (int nt = 0; nt < 2; ++nt) {
        const int r1 = (col & 3) * 64 + w * 8 + nt * 4 + (col >> 2);
        #pragma unroll
        for (int ks = 0; ks < 3; ++ks) {
            #pragma unroll
            for (int j = 0; j < 8; ++j) {
                const int k = ks * 32 + quad * 8 + j;
                float wv;
                if      (k < IN_F)       wv = Wih1[r1 * IN_F + k];
                else if (k < IN_F + H1)  wv = Whh1[r1 * H1 + (k - IN_F)];
                else if (k == IN_F + H1) wv = bih1[r1] + bhh1[r1];   // bias col
                else                     wv = 0.f;
                const unsigned short hh = bf16_rne(wv);
                wf1h[nt][ks].u[j] = hh;
                wf1l[nt][ks].u[j] = bf16_rne(wv - bf16_f(hh));
            }
        }
    }
    {
        const int r2 = (col & 3) * 32 + w * 4 + (col >> 2);
        #pragma unroll
        for (int ks = 0; ks < 4; ++ks) {
            #pragma unroll
            for (int j = 0; j < 8; ++j) {
                const int k = ks * 32 + quad * 8 + j;
                float wv;
                if      (k >= IN_F && k < IN_F + H1) wv = Wih2[r2 * H1 + (k - IN_F)];
                else if (k == IN_F + H1)             wv = bih2[r2] + bhh2[r2]; // bias col
                else if (k >= 96)                    wv = Whh2[r2 * H2 + (k - 96)];
                else                                 wv = 0.f;
                const unsigned short hh = bf16_rne(wv);
                wf2h[ks].u[j] = hh;
                wf2l[ks].u[j] = bf16_rne(wv - bf16_f(hh));
            }
        }
    }
    // ---- PIN all fragments into AGPRs (kills in-loop rematerialization) ----
    #pragma unroll
    for (int nt = 0; nt < 2; ++nt)
        #pragma unroll
        for (int ks = 0; ks < 3; ++ks) { APIN4(wf1h[nt][ks]); APIN4(wf1l[nt][ks]); }
    #pragma unroll
    for (int ks = 0; ks < 4; ++ks) { APIN4(wf2h[ks]); APIN4(wf2l[ks]); }

    // ---- init LDS: zero z; bias-one col (both pp); x(0) ----
    {
        int* pz = (int*)zz;
        #pragma unroll
        for (int i = 0; i < 8; ++i) pz[t + i * BLK] = 0;
    }
    __syncthreads();
    if (t < 16) {                           // off(k=68,n) = 1024 + n*8 + 4
        zz[0][0][1024 + t * 8 + 4] = 0x3F80;
        zz[1][0][1024 + t * 8 + 4] = 0x3F80;
    }
    if (t < MB * IN_F) {
        const int n = t >> 2, f = t & 3;
        const float xv = x[(size_t)(b0 + n) * T_LEN * IN_F + f];
        const unsigned short xh = bf16_rne(xv);
        zz[0][0][n * 8 + f] = xh;           // off(k=f,n) = n*8 + f
        zz[0][1][n * 8 + f] = bf16_rne(xv - bf16_f(xh));
    }
    float c1[2] = {0.f, 0.f};   // layer1 units w*8+nt*4+quad, batch col
    float c2    = 0.f;          // layer2 unit  w*4+quad,      batch col

    // precomputed store offsets (element index)
    const int u1a  = w * 8 + quad;                 // nt=0 unit
    const int u1b  = w * 8 + 4 + quad;             // nt=1 unit
    const int kA0  = IN_F + u1a, kA1 = IN_F + u1b;
    const int off1a = (kA0 >> 5) * 512 + (((kA0 >> 3) & 3) * 16 + col) * 8 + (kA0 & 7);
    const int off1b = (kA1 >> 5) * 512 + (((kA1 >> 3) & 3) * 16 + col) * 8 + (kA1 & 7);
    const int u2    = w * 4 + quad;
    const int off2  = 1536 + (((u2 >> 3) & 3) * 16 + col) * 8 + (u2 & 7);
    const int offF  = lane * 8;                    // frag read base
    __syncthreads();

    // ================= main recurrence: ONE barrier per step =================
    #pragma unroll 1
    for (int s = 0; s < T_LEN; ++s) {
        const int p = s & 1, np = p ^ 1;

        float xnext = 0.f;
        if (t < MB * IN_F && s < T_LEN - 1)
            xnext = x[(size_t)(b0 + (t >> 2)) * T_LEN * IN_F + (s + 1) * IN_F + (t & 3)];

        // ---- fragment reads (contiguous lane*16B; conflict-free per R7) ----
        s8b zh[4], zl[4];
        #pragma unroll
        for (int ks = 0; ks < 4; ++ks) {
            zh[ks] = *(const s8b*)(&zz[p][0][0] + ks * 512 + offF);
            zl[ks] = *(const s8b*)(&zz[p][1][0] + ks * 512 + offF);
        }

        // ---- MFMA burst: gates1(s) (2 tiles) + gates2(s-1) (1 tile) ----
        f4 acc1[2] = {{0,0,0,0},{0,0,0,0}};
        f4 acc2 = {0,0,0,0};
        #pragma unroll
        for (int ks = 0; ks < 3; ++ks) {
            #pragma unroll
            for (int nt = 0; nt < 2; ++nt) {
                acc1[nt] = __builtin_amdgcn_mfma_f32_16x16x32_bf16(wf1h[nt][ks].v, zh[ks], acc1[nt], 0, 0, 0);
                acc1[nt] = __builtin_amdgcn_mfma_f32_16x16x32_bf16(wf1h[nt][ks].v, zl[ks], acc1[nt], 0, 0, 0);
                acc1[nt] = __builtin_amdgcn_mfma_f32_16x16x32_bf16(wf1l[nt][ks].v, zh[ks], acc1[nt], 0, 0, 0);
            }
        }
        #pragma unroll
        for (int ks = 0; ks < 4; ++ks) {
            acc2 = __builtin_amdgcn_mfma_f32_16x16x32_bf16(wf2h[ks].v, zh[ks], acc2, 0, 0, 0);
            acc2 = __builtin_amdgcn_mfma_f32_16x16x32_bf16(wf2h[ks].v, zl[ks], acc2, 0, 0, 0);
            acc2 = __builtin_amdgcn_mfma_f32_16x16x32_bf16(wf2l[ks].v, zh[ks], acc2, 0, 0, 0);
        }

        // ---- layer1 activations in-register (acc[rg] = gate rg: i,f,g,o) ----
        #pragma unroll
        for (int nt = 0; nt < 2; ++nt) {
            const float I = sigm(acc1[nt][0]);
            const float F = sigm(acc1[nt][1]);
            const float G = tanh_(acc1[nt][2]);
            const float O = sigm(acc1[nt][3]);
            c1[nt] = fmaf(F, c1[nt], I * G);
            const float h = O * tanh_(c1[nt]);
            const unsigned short hh = bf16_rne(h);
            const unsigned short hl = bf16_rne(h - bf16_f(hh));
            if (col < MB) {
                const int o = nt ? off1b : off1a;
                zz[np][0][o] = hh;
                zz[np][1][o] = hl;
            }
        }

        // ---- layer2 activation for step s-1 (bias came via bias column) ----
        if (s > 0) {
            const float I = sigm(acc2[0]);
            const float F = sigm(acc2[1]);
            const float G = tanh_(acc2[2]);
            const float O = sigm(acc2[3]);
            c2 = fmaf(F, c2, I * G);
            const float h = O * tanh_(c2);
            if (col < MB) {
                const unsigned short hh = bf16_rne(h);
                zz[np][0][off2] = hh;
                zz[np][1][off2] = bf16_rne(h - bf16_f(hh));
            }
        }

        // ---- x(s+1) ----
        if (t < MB * IN_F && s < T_LEN - 1) {
            const unsigned short xh = bf16_rne(xnext);
            zz[np][0][(t >> 2) * 8 + (t & 3)] = xh;
            zz[np][1][(t >> 2) * 8 + (t & 3)] = bf16_rne(xnext - bf16_f(xh));
        }
        __syncthreads();
    }

    // ================= epilogue: layer2 step T-1 =================
    {
        // loop ended with s=511 (p=1, np=0): z[0] holds h1(511), h2(510).
        s8b zh[4], zl[4];
        #pragma unroll
        for (int ks = 0; ks < 4; ++ks) {
            zh[ks] = *(const s8b*)(&zz[0][0][0] + ks * 512 + offF);
            zl[ks] = *(const s8b*)(&zz[0][1][0] + ks * 512 + offF);
        }
        f4 acc2 = {0,0,0,0};
        #pragma unroll
        for (int ks = 0; ks < 4; ++ks) {
            acc2 = __builtin_amdgcn_mfma_f32_16x16x32_bf16(wf2h[ks].v, zh[ks], acc2, 0, 0, 0);
            acc2 = __builtin_amdgcn_mfma_f32_16x16x32_bf16(wf2h[ks].v, zl[ks], acc2, 0, 0, 0);
            acc2 = __builtin_amdgcn_mfma_f32_16x16x32_bf16(wf2l[ks].v, zh[ks], acc2, 0, 0, 0);
        }
        const float I = sigm(acc2[0]);
        const float F = sigm(acc2[1]);
        const float G = tanh_(acc2[2]);
        const float O = sigm(acc2[3]);
        c2 = fmaf(F, c2, I * G);
        if (col < MB) h2f[col * H2 + u2] = O * tanh_(c2);
    }
    __syncthreads();

    // ================= FC head =================
    if (t < MB * FCN) {
        const int b = t >> 4, j = t & 15;
        float s1 = fc1_b[j];
        #pragma unroll
        for (int k = 0; k < H2; ++k)
            s1 = fmaf(fc1_w[j * H2 + k], h2f[b * H2 + k], s1);
        fcs[b * FCN + j] = fmaxf(s1, 0.f);
    }
    __syncthreads();
    if (t < MB) {
        float s2 = fc2_b[0];
        #pragma unroll
        for (int j = 0; j < FCN; ++j)
            s2 = fmaf(fc2_w[j], fcs[t * FCN + j], s2);
        out[b0 + t] = s2;
    }
}

extern "C" void kernel_launch(void* const* d_in, const int* in_sizes, int n_in,
                              void* d_out, int out_size, void* d_ws, size_t ws_size,
                              hipStream_t stream) {
    const float* x     = (const float*)d_in[0];
    const float* Wih1  = (const float*)d_in[1];
    const float* Whh1  = (const float*)d_in[2];
    const float* bih1  = (const float*)d_in[3];
    const float* bhh1  = (const float*)d_in[4];
    const float* Wih2  = (const float*)d_in[5];
    const float* Whh2  = (const float*)d_in[6];
    const float* bih2  = (const float*)d_in[7];
    const float* bhh2  = (const float*)d_in[8];
    const float* fc1_w = (const float*)d_in[9];
    const float* fc1_b = (const float*)d_in[10];
    const float* fc2_w = (const float*)d_in[11];
    const float* fc2_b = (const float*)d_in[12];
    float* out = (float*)d_out;

    const int n_batch = 2048;
    dim3 grid(n_batch / MB), block(BLK);
    lstm_mfma<<<grid, block, 0, stream>>>(x, Wih1, Whh1, bih1, bhh1,
                                          Wih2, Whh2, bih2, bhh2,
                                          fc1_w, fc1_b, fc2_w, fc2_b, out);
}